// Round 5
// baseline (207.261 us; speedup 1.0000x reference)
//
#include <hip/hip_runtime.h>
#include <hip/hip_bf16.h>

#define NSP 4096   // spatial points = 16*16*16
#define QSCALE 0.17677669529663687f   // 1/sqrt(32)
#define QSC2   0.25503486f            // log2(e)/sqrt(32)  (exp->exp2 folding)

typedef __attribute__((ext_vector_type(8))) short bf16x8;
typedef __attribute__((ext_vector_type(4))) float f32x4;

__device__ __forceinline__ unsigned short f2bf(float f){
  union{float f;unsigned int u;}c; c.f=f;
  unsigned int r = c.u + 0x7fffu + ((c.u>>16)&1u);
  return (unsigned short)(r>>16);
}
__device__ __forceinline__ unsigned int pk2(float a, float b){
  __hip_bfloat162 p = __float22bfloat162_rn(make_float2(a, b));
  unsigned int r; __builtin_memcpy(&r, &p, 4); return r;
}
__device__ __forceinline__ ushort4 pk4(float a, float b, float c, float d){
  union { ushort4 u4; uint2 u2; } u;
  u.u2.x = pk2(a, b); u.u2.y = pk2(c, d);
  return u.u4;
}

// ---------------------------------------------------------------------------
// Kernel 1a: depthwise 3x3x3 conv + bias; y fp32 [c][n] (coalesced) + per-
// channel stats (rinv, -mean*rinv). One block per channel, 512 threads.
// ---------------------------------------------------------------------------
__global__ __launch_bounds__(512) void k_dwconv(
    const float* __restrict__ x,
    const float* __restrict__ wdw,
    const float* __restrict__ bdw,
    float* __restrict__ y, float2* __restrict__ stats)
{
  const int c = blockIdx.x;
  const int tid = threadIdx.x;
  __shared__ float xs[4096];
  __shared__ float wsh[27];
  __shared__ float bsh;
  __shared__ float rs[8], rq[8];

  const float* xc = x + (size_t)c * NSP;
  for (int i = tid; i < 1024; i += 512) *(float4*)&xs[i*4] = ((const float4*)xc)[i];
  if (tid < 27) wsh[tid] = wdw[c*27 + tid];
  if (tid == 31) bsh = bdw[c];
  __syncthreads();

  float yv[8];
  float sum = 0.f, sumsq = 0.f;
  #pragma unroll
  for (int i = 0; i < 8; i++){
    const int n = (i << 9) + tid;
    const int h = n >> 8, w = (n >> 4) & 15, d = n & 15;
    float acc = bsh;
    #pragma unroll
    for (int kh = 0; kh < 3; kh++){
      const int hh = h + kh - 1;
      if ((unsigned)hh >= 16u) continue;
      #pragma unroll
      for (int kw = 0; kw < 3; kw++){
        const int ww = w + kw - 1;
        if ((unsigned)ww >= 16u) continue;
        #pragma unroll
        for (int kd = 0; kd < 3; kd++){
          const int dd = d + kd - 1;
          if ((unsigned)dd >= 16u) continue;
          acc += wsh[kh*9 + kw*3 + kd] * xs[(hh<<8) + (ww<<4) + dd];
        }
      }
    }
    yv[i] = acc; sum += acc; sumsq += acc*acc;
  }
  #pragma unroll
  for (int off = 32; off > 0; off >>= 1){
    sum   += __shfl_down(sum, off, 64);
    sumsq += __shfl_down(sumsq, off, 64);
  }
  const int wid = tid >> 6, lane = tid & 63;
  if (lane == 0){ rs[wid] = sum; rq[wid] = sumsq; }
  __syncthreads();
  float ts = 0.f, tq = 0.f;
  #pragma unroll
  for (int i = 0; i < 8; i++){ ts += rs[i]; tq += rq[i]; }
  const float mean = ts * (1.f/4096.f);
  const float var  = tq * (1.f/4096.f) - mean*mean;
  const float rinv = rsqrtf(var + 1e-5f);
  float* yo = y + (size_t)c * NSP;
  #pragma unroll
  for (int i = 0; i < 8; i++) yo[(i<<9) + tid] = yv[i];
  if (tid == 0) stats[c] = make_float2(rinv, -mean*rinv);
}

// ---------------------------------------------------------------------------
// Kernel 1b: normalize + transpose -> bf16 ynT[n][c]. 64x64 tiles via LDS;
// 16B-coalesced global loads AND stores.
// ---------------------------------------------------------------------------
__global__ __launch_bounds__(256) void k_ynormT(
    const float* __restrict__ y, const float2* __restrict__ stats,
    unsigned short* __restrict__ ynT)
{
  __shared__ unsigned short T[64][72];
  const int tid = threadIdx.x;
  const int n0 = blockIdx.x * 64, c0 = blockIdx.y * 64;
  const int cl = tid >> 4, n4 = (tid & 15) * 4;
  #pragma unroll
  for (int i = 0; i < 4; i++){
    const int c = cl + i*16;
    const float2 ab = stats[c0 + c];
    const float4 v = *(const float4*)(y + (size_t)(c0 + c) * NSP + n0 + n4);
    T[n4+0][c] = f2bf(v.x*ab.x + ab.y);
    T[n4+1][c] = f2bf(v.y*ab.x + ab.y);
    T[n4+2][c] = f2bf(v.z*ab.x + ab.y);
    T[n4+3][c] = f2bf(v.w*ab.x + ab.y);
  }
  __syncthreads();
  const int nl = tid >> 2, s8 = (tid & 3) * 8;
  *(uint4*)(ynT + (size_t)(n0+nl)*256 + c0 + s8)      = *(const uint4*)&T[nl][s8];
  *(uint4*)(ynT + (size_t)(n0+nl)*256 + c0 + s8 + 32) = *(const uint4*)&T[nl][s8 + 32];
}

// ---------------------------------------------------------------------------
// Kernel 2: MFMA QKV GEMM from bf16 ynT[n][c] and fp32 W[o][c].
// Block: 64 o x 128 n, 4 waves. W staged bf16 in LDS.
// q pre-scaled by log2(e)/sqrt(hd) (softmax uses exp2).
// ---------------------------------------------------------------------------
__global__ __launch_bounds__(256) void k_qkv(
    const float* __restrict__ wqkv,
    const float* __restrict__ bqkv,
    const unsigned short* __restrict__ ynT,
    unsigned short* __restrict__ qb, unsigned short* __restrict__ kb,
    unsigned short* __restrict__ vbt)
{
  __shared__ unsigned short Wb[64][264];
  const int tid = threadIdx.x;
  const int o0 = blockIdx.y * 64;
  const int n0 = blockIdx.x * 128;
  {
    const int row = tid & 63, part = tid >> 6;
    const float* src = wqkv + (size_t)(o0 + row) * 256 + part * 64;
    unsigned short* dst = &Wb[row][part*64];
    #pragma unroll
    for (int j = 0; j < 8; j++){
      const float4 a = ((const float4*)src)[2*j];
      const float4 b = ((const float4*)src)[2*j+1];
      *(ushort4*)&dst[j*8]     = pk4(a.x, a.y, a.z, a.w);
      *(ushort4*)&dst[j*8 + 4] = pk4(b.x, b.y, b.z, b.w);
    }
  }
  __syncthreads();

  const int w = tid >> 6, lane = tid & 63, quad = lane >> 4, cc = lane & 15;
  const int nbase = n0 + w*32;
  const bool isv = (o0 >= 512);
  f32x4 acc[2][4] = {};

  #pragma unroll
  for (int k = 0; k < 8; k++){
    const bf16x8 y0 = *(const bf16x8*)(ynT + (size_t)(nbase + cc)  * 256 + k*32 + quad*8);
    const bf16x8 y1 = *(const bf16x8*)(ynT + (size_t)(nbase+16+cc) * 256 + k*32 + quad*8);
    #pragma unroll
    for (int os = 0; os < 4; os++){
      const bf16x8 wf = *(const bf16x8*)&Wb[os*16 + cc][k*32 + quad*8];
      if (!isv){
        acc[0][os] = __builtin_amdgcn_mfma_f32_16x16x32_bf16(y0, wf, acc[0][os], 0, 0, 0);
        acc[1][os] = __builtin_amdgcn_mfma_f32_16x16x32_bf16(y1, wf, acc[1][os], 0, 0, 0);
      } else {
        acc[0][os] = __builtin_amdgcn_mfma_f32_16x16x32_bf16(wf, y0, acc[0][os], 0, 0, 0);
        acc[1][os] = __builtin_amdgcn_mfma_f32_16x16x32_bf16(wf, y1, acc[1][os], 0, 0, 0);
      }
    }
  }

  if (!isv){
    #pragma unroll
    for (int os = 0; os < 4; os++){
      const int o = o0 + os*16 + cc;
      const int g = o >> 8, hh = (o >> 5) & 7, dd = o & 31;
      const float bias = bqkv[o];
      const float sc = (g == 0) ? QSC2 : 1.f;
      unsigned short* dst = (g == 0) ? qb : kb;
      #pragma unroll
      for (int ns = 0; ns < 2; ns++){
        #pragma unroll
        for (int r = 0; r < 4; r++){
          const int n = nbase + ns*16 + quad*4 + r;
          dst[((size_t)hh * NSP + n) * 32 + dd] = f2bf((acc[ns][os][r] + bias) * sc);
        }
      }
    }
  } else {
    #pragma unroll
    for (int os = 0; os < 4; os++){
      #pragma unroll
      for (int r = 0; r < 4; r++){
        const int orow = o0 - 512 + os*16 + quad*4 + r;   // = h*32+dd
        const float bias = bqkv[512 + orow];
        #pragma unroll
        for (int ns = 0; ns < 2; ns++){
          const int n = nbase + ns*16 + cc;
          vbt[(size_t)orow * NSP + n] = f2bf(acc[ns][os][r] + bias);
        }
      }
    }
  }
}

// ---------------------------------------------------------------------------
// Kernel 3: barrier-free MFMA flash attention, KV-split 2, register
// double-buffered K prefetch + hoisted V loads (latency covered by ILP).
// exp2-based softmax (log2e folded into q).
// ---------------------------------------------------------------------------
__global__ __launch_bounds__(256) void k_attn(
    const unsigned short* __restrict__ qb,
    const unsigned short* __restrict__ kb,
    const unsigned short* __restrict__ vbt,
    float* __restrict__ op, float* __restrict__ lp)
{
  const int h = blockIdx.y, q0 = blockIdx.x * 64, z = blockIdx.z;
  const int tid = threadIdx.x;
  const int w = tid >> 6, lane = tid & 63, quad = lane >> 4, cc = lane & 15;
  __shared__ unsigned short pst[64][136];   // [q_local][kcol], rows wave-private

  const bf16x8 qf = *(const bf16x8*)(qb + ((size_t)(h * NSP + q0 + w*16 + cc)) * 32 + quad*8);
  const unsigned short* kbase = kb  + (size_t)h * NSP * 32;
  const unsigned short* vbase = vbt + (size_t)h * 32 * NSP;

  f32x4 o0 = {0.f,0.f,0.f,0.f}, o1 = {0.f,0.f,0.f,0.f};
  float lsum = 0.f;

  const int kt0 = z << 11;
  bf16x8 kfb[2][8];
  #pragma unroll
  for (int t = 0; t < 8; t++)
    kfb[0][t] = *(const bf16x8*)(kbase + (size_t)(kt0 + t*16 + cc) * 32 + quad*8);

  #pragma unroll 2
  for (int it = 0; it < 16; it++){
    const int kt = kt0 + it * 128;
    const int cur = it & 1;

    // hoisted V loads (consumed after softmax, ~2/3 iter of cover)
    bf16x8 va[4], vb2[4];
    #pragma unroll
    for (int ch = 0; ch < 4; ch++){
      va[ch]  = *(const bf16x8*)(vbase + (size_t)cc        * NSP + kt + ch*32 + quad*8);
      vb2[ch] = *(const bf16x8*)(vbase + (size_t)(16 + cc) * NSP + kt + ch*32 + quad*8);
    }
    // prefetch next K tile (consumed next iteration, full iter of cover)
    const int ktn = (it == 15) ? kt0 : kt + 128;
    #pragma unroll
    for (int t = 0; t < 8; t++)
      kfb[cur ^ 1][t] = *(const bf16x8*)(kbase + (size_t)(ktn + t*16 + cc) * 32 + quad*8);

    // S^T = K*Q^T per 16-col tile; exp2; pack; pst write (fused, high ILP)
    #pragma unroll
    for (int t = 0; t < 8; t++){
      f32x4 a = {0.f,0.f,0.f,0.f};
      a = __builtin_amdgcn_mfma_f32_16x16x32_bf16(kfb[cur][t], qf, a, 0, 0, 0);
      const float p0 = exp2f(a.x), p1 = exp2f(a.y);
      const float p2 = exp2f(a.z), p3 = exp2f(a.w);
      lsum += (p0 + p1) + (p2 + p3);
      *(ushort4*)&pst[w*16 + cc][t*16 + quad*4] = pk4(p0, p1, p2, p3);
    }
    // O^T += V^T * P^T
    #pragma unroll
    for (int ch = 0; ch < 4; ch++){
      const bf16x8 pf = *(const bf16x8*)&pst[w*16 + cc][ch*32 + quad*8];
      o0 = __builtin_amdgcn_mfma_f32_16x16x32_bf16(va[ch],  pf, o0, 0, 0, 0);
      o1 = __builtin_amdgcn_mfma_f32_16x16x32_bf16(vb2[ch], pf, o1, 0, 0, 0);
    }
  }

  lsum += __shfl_xor(lsum, 16, 64);
  lsum += __shfl_xor(lsum, 32, 64);

  const int n = q0 + w*16 + cc;
  float* dst = op + ((size_t)z * NSP + n) * 256 + h*32;
  *(f32x4*)(dst + quad*4)      = o0;
  *(f32x4*)(dst + 16 + quad*4) = o1;
  if (quad == 0) lp[(size_t)z * 8 * NSP + h * NSP + n] = lsum;
}

// ---------------------------------------------------------------------------
// Kernel 4: fused combine + output projection. Reads split partials op/lp,
// normalizes into bf16 B-fragments in registers, MFMA with W, fp32 out[o][n].
// ---------------------------------------------------------------------------
__global__ __launch_bounds__(256) void k_proj(
    const float* __restrict__ wproj,
    const float* __restrict__ bproj,
    const float* __restrict__ op,
    const float* __restrict__ lp,
    float* __restrict__ out)
{
  __shared__ unsigned short Wb[64][264];
  const int tid = threadIdx.x;
  const int o0 = blockIdx.y * 64;
  const int n0 = blockIdx.x * 128;
  {
    const int row = tid & 63, part = tid >> 6;
    const float* src = wproj + (size_t)(o0 + row) * 256 + part * 64;
    unsigned short* dst = &Wb[row][part*64];
    #pragma unroll
    for (int j = 0; j < 8; j++){
      const float4 a = ((const float4*)src)[2*j];
      const float4 b = ((const float4*)src)[2*j+1];
      *(ushort4*)&dst[j*8]     = pk4(a.x, a.y, a.z, a.w);
      *(ushort4*)&dst[j*8 + 4] = pk4(b.x, b.y, b.z, b.w);
    }
  }
  __syncthreads();

  const int w = tid >> 6, lane = tid & 63, quad = lane >> 4, cc = lane & 15;
  const int nbase = n0 + w*32;
  f32x4 acc[2][4] = {};

  #pragma unroll
  for (int k = 0; k < 8; k++){       // k = c-chunk = head index
    const int n0r = nbase + cc, n1r = nbase + 16 + cc;
    const float r0 = 1.f / (lp[(size_t)k*NSP + n0r] + lp[(size_t)(8+k)*NSP + n0r]);
    const float r1 = 1.f / (lp[(size_t)k*NSP + n1r] + lp[(size_t)(8+k)*NSP + n1r]);
    const float* pa0 = op + (size_t)n0r * 256 + k*32 + quad*8;
    const float* pb0 = op + (size_t)(NSP + n0r) * 256 + k*32 + quad*8;
    const float* pa1 = op + (size_t)n1r * 256 + k*32 + quad*8;
    const float* pb1 = op + (size_t)(NSP + n1r) * 256 + k*32 + quad*8;
    const float4 a0 = ((const float4*)pa0)[0], a1 = ((const float4*)pa0)[1];
    const float4 b0 = ((const float4*)pb0)[0], b1 = ((const float4*)pb0)[1];
    const float4 c0 = ((const float4*)pa1)[0], c1 = ((const float4*)pa1)[1];
    const float4 d0 = ((const float4*)pb1)[0], d1 = ((const float4*)pb1)[1];
    union { bf16x8 v; ushort4 u[2]; } y0u, y1u;
    y0u.u[0] = pk4((a0.x+b0.x)*r0, (a0.y+b0.y)*r0, (a0.z+b0.z)*r0, (a0.w+b0.w)*r0);
    y0u.u[1] = pk4((a1.x+b1.x)*r0, (a1.y+b1.y)*r0, (a1.z+b1.z)*r0, (a1.w+b1.w)*r0);
    y1u.u[0] = pk4((c0.x+d0.x)*r1, (c0.y+d0.y)*r1, (c0.z+d0.z)*r1, (c0.w+d0.w)*r1);
    y1u.u[1] = pk4((c1.x+d1.x)*r1, (c1.y+d1.y)*r1, (c1.z+d1.z)*r1, (c1.w+d1.w)*r1);
    #pragma unroll
    for (int os = 0; os < 4; os++){
      const bf16x8 wf = *(const bf16x8*)&Wb[os*16 + cc][k*32 + quad*8];
      acc[0][os] = __builtin_amdgcn_mfma_f32_16x16x32_bf16(wf, y0u.v, acc[0][os], 0, 0, 0);
      acc[1][os] = __builtin_amdgcn_mfma_f32_16x16x32_bf16(wf, y1u.v, acc[1][os], 0, 0, 0);
    }
  }

  #pragma unroll
  for (int os = 0; os < 4; os++){
    #pragma unroll
    for (int r = 0; r < 4; r++){
      const int o = o0 + os*16 + quad*4 + r;
      const float bias = bproj[o];
      #pragma unroll
      for (int ns = 0; ns < 2; ns++){
        const int n = nbase + ns*16 + cc;
        out[(size_t)o * NSP + n] = acc[ns][os][r] + bias;
      }
    }
  }
}

// ---------------------------------------------------------------------------
extern "C" void kernel_launch(void* const* d_in, const int* in_sizes, int n_in,
                              void* d_out, int out_size, void* d_ws, size_t ws_size,
                              hipStream_t stream) {
  (void)in_sizes; (void)n_in; (void)out_size; (void)ws_size;
  const float* x     = (const float*)d_in[0];
  const float* wdw   = (const float*)d_in[1];
  const float* bdw   = (const float*)d_in[2];
  const float* wqkv  = (const float*)d_in[3];
  const float* bqkv  = (const float*)d_in[4];
  const float* wproj = (const float*)d_in[5];
  const float* bproj = (const float*)d_in[6];
  float* out = (float*)d_out;

  char* ws = (char*)d_ws;
  // op (written by k_attn) overlaps y/ynT (dead after k_qkv).
  float*          op    = (float*)ws;                      // 8 MB fp32 [2][n][256]
  float*          y     = (float*)ws;                      // 4 MB fp32 [c][n]
  unsigned short* ynT   = (unsigned short*)(ws + (4<<20)); // 2 MB bf16 [n][c]
  unsigned short* qb    = (unsigned short*)(ws + (8<<20)); // 2 MB bf16 [h][n][32]
  unsigned short* kb    = (unsigned short*)(ws + (10<<20));
  unsigned short* vbt   = (unsigned short*)(ws + (12<<20));
  float*          lp    = (float*)(ws + (14<<20));         // 256 KB [2][h][n]
  float2*         stats = (float2*)(ws + (14<<20) + (256<<10));

  k_dwconv <<<dim3(256),      dim3(512), 0, stream>>>(x, wdw, bdw, y, stats);
  k_ynormT <<<dim3(64, 4),    dim3(256), 0, stream>>>(y, stats, ynT);
  k_qkv    <<<dim3(32, 12),   dim3(256), 0, stream>>>(wqkv, bqkv, ynT, qb, kb, vbt);
  k_attn   <<<dim3(64, 8, 2), dim3(256), 0, stream>>>(qb, kb, vbt, op, lp);
  k_proj   <<<dim3(32, 4),    dim3(256), 0, stream>>>(wproj, bproj, op, lp, out);
}

// Round 6
// 161.752 us; speedup vs baseline: 1.2814x; 1.2814x over previous
//
#include <hip/hip_runtime.h>
#include <hip/hip_bf16.h>

#define NSP 4096   // spatial points = 16*16*16
#define QSC2 0.25503486f   // log2(e)/sqrt(32): folded so softmax uses exp2

typedef __attribute__((ext_vector_type(8))) short bf16x8;
typedef __attribute__((ext_vector_type(4))) float f32x4;

__device__ __forceinline__ unsigned short f2bf(float f){
  union{float f;unsigned int u;}c; c.f=f;
  unsigned int r = c.u + 0x7fffu + ((c.u>>16)&1u);
  return (unsigned short)(r>>16);
}
__device__ __forceinline__ unsigned int pk2(float a, float b){
  __hip_bfloat162 p = __float22bfloat162_rn(make_float2(a, b));
  unsigned int r; __builtin_memcpy(&r, &p, 4); return r;
}
__device__ __forceinline__ ushort4 pk4(float a, float b, float c, float d){
  union { ushort4 u4; uint2 u2; } u;
  u.u2.x = pk2(a, b); u.u2.y = pk2(c, d);
  return u.u4;
}

// ---------------------------------------------------------------------------
// Kernel 1: depthwise 3x3x3 conv + bias + InstanceNorm -> normalized bf16
// ybn[c][n] (coalesced). One block per channel, 512 threads.
// ---------------------------------------------------------------------------
__global__ __launch_bounds__(512) void k_dwconv(
    const float* __restrict__ x,
    const float* __restrict__ wdw,
    const float* __restrict__ bdw,
    unsigned short* __restrict__ ybn)
{
  const int c = blockIdx.x;
  const int tid = threadIdx.x;
  __shared__ float xs[4096];
  __shared__ float wsh[27];
  __shared__ float bsh;
  __shared__ float rs[8], rq[8];

  const float* xc = x + (size_t)c * NSP;
  for (int i = tid; i < 1024; i += 512) *(float4*)&xs[i*4] = ((const float4*)xc)[i];
  if (tid < 27) wsh[tid] = wdw[c*27 + tid];
  if (tid == 31) bsh = bdw[c];
  __syncthreads();

  float yv[8];
  float sum = 0.f, sumsq = 0.f;
  #pragma unroll
  for (int i = 0; i < 8; i++){
    const int n = (i << 9) + tid;
    const int h = n >> 8, w = (n >> 4) & 15, d = n & 15;
    float acc = bsh;
    #pragma unroll
    for (int kh = 0; kh < 3; kh++){
      const int hh = h + kh - 1;
      if ((unsigned)hh >= 16u) continue;
      #pragma unroll
      for (int kw = 0; kw < 3; kw++){
        const int ww = w + kw - 1;
        if ((unsigned)ww >= 16u) continue;
        #pragma unroll
        for (int kd = 0; kd < 3; kd++){
          const int dd = d + kd - 1;
          if ((unsigned)dd >= 16u) continue;
          acc += wsh[kh*9 + kw*3 + kd] * xs[(hh<<8) + (ww<<4) + dd];
        }
      }
    }
    yv[i] = acc; sum += acc; sumsq += acc*acc;
  }
  #pragma unroll
  for (int off = 32; off > 0; off >>= 1){
    sum   += __shfl_down(sum, off, 64);
    sumsq += __shfl_down(sumsq, off, 64);
  }
  const int wid = tid >> 6, lane = tid & 63;
  if (lane == 0){ rs[wid] = sum; rq[wid] = sumsq; }
  __syncthreads();
  float ts = 0.f, tq = 0.f;
  #pragma unroll
  for (int i = 0; i < 8; i++){ ts += rs[i]; tq += rq[i]; }
  const float mean = ts * (1.f/4096.f);
  const float var  = tq * (1.f/4096.f) - mean*mean;
  const float rinv = rsqrtf(var + 1e-5f);
  unsigned short* yo = ybn + (size_t)c * NSP;
  #pragma unroll
  for (int i = 0; i < 8; i++) yo[(i<<9) + tid] = f2bf((yv[i] - mean) * rinv);
}

// ---------------------------------------------------------------------------
// Kernel 1b: bf16 transpose ybn[c][n] -> ynT[n][c], 64x64 tiles via LDS.
// ---------------------------------------------------------------------------
__global__ __launch_bounds__(256) void k_trans(
    const unsigned short* __restrict__ ybn,
    unsigned short* __restrict__ ynT)
{
  __shared__ unsigned short T[64][72];
  const int tid = threadIdx.x;
  const int n0 = blockIdx.x * 64, c0 = blockIdx.y * 64;
  const int cl = tid >> 4, n4 = (tid & 15) * 4;
  #pragma unroll
  for (int i = 0; i < 4; i++){
    const int c = cl + i*16;
    const ushort4 v = *(const ushort4*)(ybn + (size_t)(c0 + c) * NSP + n0 + n4);
    T[n4+0][c] = v.x; T[n4+1][c] = v.y; T[n4+2][c] = v.z; T[n4+3][c] = v.w;
  }
  __syncthreads();
  const int nl = tid >> 2, s8 = (tid & 3) * 16;
  *(uint4*)(ynT + (size_t)(n0+nl)*256 + c0 + s8)     = *(const uint4*)&T[nl][s8];
  *(uint4*)(ynT + (size_t)(n0+nl)*256 + c0 + s8 + 8) = *(const uint4*)&T[nl][s8 + 8];
}

// ---------------------------------------------------------------------------
// Kernel 2: MFMA QKV GEMM from bf16 ynT[n][c] and fp32 W[o][c].
// Block: 64 o x 128 n, 4 waves. W staged bf16 in LDS.
// q pre-scaled by log2(e)/sqrt(hd) (softmax uses exp2).
// ---------------------------------------------------------------------------
__global__ __launch_bounds__(256) void k_qkv(
    const float* __restrict__ wqkv,
    const float* __restrict__ bqkv,
    const unsigned short* __restrict__ ynT,
    unsigned short* __restrict__ qb, unsigned short* __restrict__ kb,
    unsigned short* __restrict__ vbt)
{
  __shared__ unsigned short Wb[64][264];
  const int tid = threadIdx.x;
  const int o0 = blockIdx.y * 64;
  const int n0 = blockIdx.x * 128;
  {
    const int row = tid & 63, part = tid >> 6;
    const float* src = wqkv + (size_t)(o0 + row) * 256 + part * 64;
    unsigned short* dst = &Wb[row][part*64];
    #pragma unroll
    for (int j = 0; j < 8; j++){
      const float4 a = ((const float4*)src)[2*j];
      const float4 b = ((const float4*)src)[2*j+1];
      *(ushort4*)&dst[j*8]     = pk4(a.x, a.y, a.z, a.w);
      *(ushort4*)&dst[j*8 + 4] = pk4(b.x, b.y, b.z, b.w);
    }
  }
  __syncthreads();

  const int w = tid >> 6, lane = tid & 63, quad = lane >> 4, cc = lane & 15;
  const int nbase = n0 + w*32;
  const bool isv = (o0 >= 512);
  f32x4 acc[2][4] = {};

  #pragma unroll
  for (int k = 0; k < 8; k++){
    const bf16x8 y0 = *(const bf16x8*)(ynT + (size_t)(nbase + cc)  * 256 + k*32 + quad*8);
    const bf16x8 y1 = *(const bf16x8*)(ynT + (size_t)(nbase+16+cc) * 256 + k*32 + quad*8);
    #pragma unroll
    for (int os = 0; os < 4; os++){
      const bf16x8 wf = *(const bf16x8*)&Wb[os*16 + cc][k*32 + quad*8];
      if (!isv){
        acc[0][os] = __builtin_amdgcn_mfma_f32_16x16x32_bf16(y0, wf, acc[0][os], 0, 0, 0);
        acc[1][os] = __builtin_amdgcn_mfma_f32_16x16x32_bf16(y1, wf, acc[1][os], 0, 0, 0);
      } else {
        acc[0][os] = __builtin_amdgcn_mfma_f32_16x16x32_bf16(wf, y0, acc[0][os], 0, 0, 0);
        acc[1][os] = __builtin_amdgcn_mfma_f32_16x16x32_bf16(wf, y1, acc[1][os], 0, 0, 0);
      }
    }
  }

  if (!isv){
    #pragma unroll
    for (int os = 0; os < 4; os++){
      const int o = o0 + os*16 + cc;
      const int g = o >> 8, hh = (o >> 5) & 7, dd = o & 31;
      const float bias = bqkv[o];
      const float sc = (g == 0) ? QSC2 : 1.f;
      unsigned short* dst = (g == 0) ? qb : kb;
      #pragma unroll
      for (int ns = 0; ns < 2; ns++){
        #pragma unroll
        for (int r = 0; r < 4; r++){
          const int n = nbase + ns*16 + quad*4 + r;
          dst[((size_t)hh * NSP + n) * 32 + dd] = f2bf((acc[ns][os][r] + bias) * sc);
        }
      }
    }
  } else {
    #pragma unroll
    for (int os = 0; os < 4; os++){
      #pragma unroll
      for (int r = 0; r < 4; r++){
        const int orow = o0 - 512 + os*16 + quad*4 + r;   // = h*32+dd
        const float bias = bqkv[512 + orow];
        #pragma unroll
        for (int ns = 0; ns < 2; ns++){
          const int n = nbase + ns*16 + cc;
          vbt[(size_t)orow * NSP + n] = f2bf(acc[ns][os][r] + bias);
        }
      }
    }
  }
}

// ---------------------------------------------------------------------------
// Kernel 3: MFMA flash attention, LDS-staged K/V (shared by 4 waves),
// KV-split 2 (grid 1024 = 4 blocks/CU). No-max softmax with exp2 (log2e
// folded into q). Per-lane lsum; partials op[z][n][256], lp[z][h][n].
// ---------------------------------------------------------------------------
__global__ __launch_bounds__(256) void k_attn(
    const unsigned short* __restrict__ qb,
    const unsigned short* __restrict__ kb,
    const unsigned short* __restrict__ vbt,
    float* __restrict__ op, float* __restrict__ lp)
{
  const int h = blockIdx.y, q0 = blockIdx.x * 64, z = blockIdx.z;
  const int tid = threadIdx.x;
  const int w = tid >> 6, lane = tid & 63, quad = lane >> 4, cc = lane & 15;

  __shared__ unsigned short ks [128][40];   // K tile [kcol][d]
  __shared__ unsigned short vsT[32][136];   // V^T tile [d][kcol]
  __shared__ unsigned short pst[64][136];   // P^T [q_local][kcol], wave-private rows

  const bf16x8 qf = *(const bf16x8*)(qb + ((size_t)(h * NSP + q0 + w*16 + cc)) * 32 + quad*8);
  const unsigned short* kbase = kb  + (size_t)h * NSP * 32;
  const unsigned short* vbase = vbt + (size_t)h * 32 * NSP;

  f32x4 o0 = {0.f,0.f,0.f,0.f}, o1 = {0.f,0.f,0.f,0.f};
  float lsum = 0.f;

  const int kt0 = z << 11;
  const int krow = tid >> 1, kseg = (tid & 1) * 16;
  const int vd = tid >> 3,  vseg = (tid & 7) * 16;

  for (int it = 0; it < 16; it++){
    const int kt = kt0 + it * 128;
    { // stage K tile: 128 rows x 32 d, 32B/thread
      const uint4* src = (const uint4*)(kbase + (size_t)(kt + krow) * 32 + kseg);
      const uint4 a = src[0], b = src[1];
      *(uint4*)&ks[krow][kseg]     = a;
      *(uint4*)&ks[krow][kseg + 8] = b;
    }
    { // stage V^T tile: 32 rows x 128 n, 32B/thread
      const uint4* src = (const uint4*)(vbase + (size_t)vd * NSP + kt + vseg);
      const uint4 a = src[0], b = src[1];
      *(uint4*)&vsT[vd][vseg]     = a;
      *(uint4*)&vsT[vd][vseg + 8] = b;
    }
    __syncthreads();

    // S^T = K*Q^T per 16-col tile; exp2; pack into pst
    #pragma unroll
    for (int t = 0; t < 8; t++){
      const bf16x8 kf = *(const bf16x8*)&ks[t*16 + cc][quad*8];
      f32x4 a = {0.f,0.f,0.f,0.f};
      a = __builtin_amdgcn_mfma_f32_16x16x32_bf16(kf, qf, a, 0, 0, 0);
      const float p0 = exp2f(a.x), p1 = exp2f(a.y);
      const float p2 = exp2f(a.z), p3 = exp2f(a.w);
      lsum += (p0 + p1) + (p2 + p3);
      *(ushort4*)&pst[w*16 + cc][t*16 + quad*4] = pk4(p0, p1, p2, p3);
    }
    // O^T += V^T * P^T
    #pragma unroll
    for (int ch = 0; ch < 4; ch++){
      const bf16x8 pf = *(const bf16x8*)&pst[w*16 + cc][ch*32 + quad*8];
      const bf16x8 va = *(const bf16x8*)&vsT[cc]     [ch*32 + quad*8];
      const bf16x8 vb = *(const bf16x8*)&vsT[16 + cc][ch*32 + quad*8];
      o0 = __builtin_amdgcn_mfma_f32_16x16x32_bf16(va, pf, o0, 0, 0, 0);
      o1 = __builtin_amdgcn_mfma_f32_16x16x32_bf16(vb, pf, o1, 0, 0, 0);
    }
    __syncthreads();   // protect ks/vsT before next stage
  }

  lsum += __shfl_xor(lsum, 16, 64);
  lsum += __shfl_xor(lsum, 32, 64);

  const int n = q0 + w*16 + cc;
  float* dst = op + ((size_t)z * NSP + n) * 256 + h*32;
  *(f32x4*)(dst + quad*4)      = o0;
  *(f32x4*)(dst + 16 + quad*4) = o1;
  if (quad == 0) lp[(size_t)z * 8 * NSP + h * NSP + n] = lsum;
}

// ---------------------------------------------------------------------------
// Kernel 4: fused combine + output projection. Reads split partials op/lp,
// normalizes into bf16 B-fragments in registers, MFMA with W, fp32 out[o][n].
// ---------------------------------------------------------------------------
__global__ __launch_bounds__(256) void k_proj(
    const float* __restrict__ wproj,
    const float* __restrict__ bproj,
    const float* __restrict__ op,
    const float* __restrict__ lp,
    float* __restrict__ out)
{
  __shared__ unsigned short Wb[64][264];
  const int tid = threadIdx.x;
  const int o0 = blockIdx.y * 64;
  const int n0 = blockIdx.x * 128;
  {
    const int row = tid & 63, part = tid >> 6;
    const float* src = wproj + (size_t)(o0 + row) * 256 + part * 64;
    unsigned short* dst = &Wb[row][part*64];
    #pragma unroll
    for (int j = 0; j < 8; j++){
      const float4 a = ((const float4*)src)[2*j];
      const float4 b = ((const float4*)src)[2*j+1];
      *(ushort4*)&dst[j*8]     = pk4(a.x, a.y, a.z, a.w);
      *(ushort4*)&dst[j*8 + 4] = pk4(b.x, b.y, b.z, b.w);
    }
  }
  __syncthreads();

  const int w = tid >> 6, lane = tid & 63, quad = lane >> 4, cc = lane & 15;
  const int nbase = n0 + w*32;
  f32x4 acc[2][4] = {};

  #pragma unroll
  for (int k = 0; k < 8; k++){       // k = c-chunk = head index
    const int n0r = nbase + cc, n1r = nbase + 16 + cc;
    const float r0 = 1.f / (lp[(size_t)k*NSP + n0r] + lp[(size_t)(8+k)*NSP + n0r]);
    const float r1 = 1.f / (lp[(size_t)k*NSP + n1r] + lp[(size_t)(8+k)*NSP + n1r]);
    const float* pa0 = op + (size_t)n0r * 256 + k*32 + quad*8;
    const float* pb0 = op + (size_t)(NSP + n0r) * 256 + k*32 + quad*8;
    const float* pa1 = op + (size_t)n1r * 256 + k*32 + quad*8;
    const float* pb1 = op + (size_t)(NSP + n1r) * 256 + k*32 + quad*8;
    const float4 a0 = ((const float4*)pa0)[0], a1 = ((const float4*)pa0)[1];
    const float4 b0 = ((const float4*)pb0)[0], b1 = ((const float4*)pb0)[1];
    const float4 c0 = ((const float4*)pa1)[0], c1 = ((const float4*)pa1)[1];
    const float4 d0 = ((const float4*)pb1)[0], d1 = ((const float4*)pb1)[1];
    union { bf16x8 v; ushort4 u[2]; } y0u, y1u;
    y0u.u[0] = pk4((a0.x+b0.x)*r0, (a0.y+b0.y)*r0, (a0.z+b0.z)*r0, (a0.w+b0.w)*r0);
    y0u.u[1] = pk4((a1.x+b1.x)*r0, (a1.y+b1.y)*r0, (a1.z+b1.z)*r0, (a1.w+b1.w)*r0);
    y1u.u[0] = pk4((c0.x+d0.x)*r1, (c0.y+d0.y)*r1, (c0.z+d0.z)*r1, (c0.w+d0.w)*r1);
    y1u.u[1] = pk4((c1.x+d1.x)*r1, (c1.y+d1.y)*r1, (c1.z+d1.z)*r1, (c1.w+d1.w)*r1);
    #pragma unroll
    for (int os = 0; os < 4; os++){
      const bf16x8 wf = *(const bf16x8*)&Wb[os*16 + cc][k*32 + quad*8];
      acc[0][os] = __builtin_amdgcn_mfma_f32_16x16x32_bf16(wf, y0u.v, acc[0][os], 0, 0, 0);
      acc[1][os] = __builtin_amdgcn_mfma_f32_16x16x32_bf16(wf, y1u.v, acc[1][os], 0, 0, 0);
    }
  }

  #pragma unroll
  for (int os = 0; os < 4; os++){
    #pragma unroll
    for (int r = 0; r < 4; r++){
      const int o = o0 + os*16 + quad*4 + r;
      const float bias = bproj[o];
      #pragma unroll
      for (int ns = 0; ns < 2; ns++){
        const int n = nbase + ns*16 + cc;
        out[(size_t)o * NSP + n] = acc[ns][os][r] + bias;
      }
    }
  }
}

// ---------------------------------------------------------------------------
extern "C" void kernel_launch(void* const* d_in, const int* in_sizes, int n_in,
                              void* d_out, int out_size, void* d_ws, size_t ws_size,
                              hipStream_t stream) {
  (void)in_sizes; (void)n_in; (void)out_size; (void)ws_size;
  const float* x     = (const float*)d_in[0];
  const float* wdw   = (const float*)d_in[1];
  const float* bdw   = (const float*)d_in[2];
  const float* wqkv  = (const float*)d_in[3];
  const float* bqkv  = (const float*)d_in[4];
  const float* wproj = (const float*)d_in[5];
  const float* bproj = (const float*)d_in[6];
  float* out = (float*)d_out;

  char* ws = (char*)d_ws;
  // op (written by k_attn) overlaps ybn/ynT (dead after k_qkv).
  float*          op  = (float*)ws;                       // 8 MB fp32 [2][n][256]
  unsigned short* ybn = (unsigned short*)ws;              // 2 MB bf16 [c][n]
  unsigned short* ynT = (unsigned short*)(ws + (2<<20));  // 2 MB bf16 [n][c]
  unsigned short* qb  = (unsigned short*)(ws + (8<<20));  // 2 MB bf16 [h][n][32]
  unsigned short* kb  = (unsigned short*)(ws + (10<<20));
  unsigned short* vbt = (unsigned short*)(ws + (12<<20));
  float*          lp  = (float*)(ws + (14<<20));          // 256 KB [2][h][n]

  k_dwconv <<<dim3(256),      dim3(512), 0, stream>>>(x, wdw, bdw, ybn);
  k_trans  <<<dim3(64, 4),    dim3(256), 0, stream>>>(ybn, ynT);
  k_qkv    <<<dim3(32, 12),   dim3(256), 0, stream>>>(wqkv, bqkv, ynT, qb, kb, vbt);
  k_attn   <<<dim3(64, 8, 2), dim3(256), 0, stream>>>(qb, kb, vbt, op, lp);
  k_proj   <<<dim3(32, 4),    dim3(256), 0, stream>>>(wproj, bproj, op, lp, out);
}